// Round 2
// baseline (163.697 us; speedup 1.0000x reference)
//
#include <hip/hip_runtime.h>
#include <cstdint>

// Problem constants (fixed by reference)
#define NB      8
#define NN      4096
#define NCLS    80
#define MAXDET  300
#define CAP     160     // per-(batch,class) list capacity; counts ~49 +/- 7 (16 sigma)

// Output float layout (flat, 16808 elements)
#define OFF_IDX  0
#define OFF_SCR  2400
#define OFF_BOX  4800
#define OFF_CLS  14400
#define OFF_NDT  16800

// Workspace layout (bytes)
#define WS_KSEG  0                          // u64 [NB*NCLS][CAP] kept keys per class (segmented)
#define WS_KNUM  (NB * NCLS * CAP * 8)      // i32 [NB*NCLS] kept count per class (single writer)
#define WS_TICK  (WS_KNUM + NB * NCLS * 4)  // i32 [NB] arrival tickets (memset to 0 each replay)

// IoU > thr test, matching reference arithmetic exactly (no FMA contraction).
__device__ __forceinline__ bool iou_gt(float c0, float c1, float c2, float c3,
                                       float t0, float t1, float t2, float t3,
                                       float tarea)
{
#pragma clang fp contract(off)
    float xx1 = fmaxf(c0, t0);
    float yy1 = fmaxf(c1, t1);
    float xx2 = fminf(c2, t2);
    float yy2 = fminf(c3, t3);
    float w = xx2 - xx1; w = fmaxf(w, 0.0f);
    float h = yy2 - yy1; h = fmaxf(h, 0.0f);
    float inter = w * h;
    float areac = (c2 - c0) * (c3 - c1);
    float uni = areac + tarea - inter;
    return (inter / uni) > 0.65f;
}

__device__ __forceinline__ uint64_t shfl_xor64(uint64_t x, int m)
{
    unsigned lo = __shfl_xor((unsigned)x, m, 64);
    unsigned hi = __shfl_xor((unsigned)(x >> 32), m, 64);
    return ((uint64_t)hi << 32) | lo;
}

__device__ __forceinline__ void ce64(uint64_t& a, uint64_t& b, bool desc)
{
    uint64_t lo = (a < b) ? a : b;
    uint64_t hi = (a < b) ? b : a;
    a = desc ? hi : lo;
    b = desc ? lo : hi;
}

// ================== single fused kernel ==================
// 640 blocks x 64 threads, one block per (batch,class):
//   phase 1: scan batch scores/classes (L2-resident), compact this class's
//            valid keys to LDS, sort, greedy NMS, write private kseg/knum.
//   phase 2: __threadfence + ticket atomicAdd; the 80th arriver for a batch
//            becomes that batch's packer: histogram -> 1-bin cutoff ->
//            <=512 candidates -> single-wave bitonic-512 -> pack outputs.
// Single-writer global stores everywhere except the ticket (memset-inited).
__global__ __launch_bounds__(64)
void k_nms_all(const float* __restrict__ scores,
               const float* __restrict__ boxes,
               const int*   __restrict__ classes,
               uint64_t*    __restrict__ kseg,
               int*         __restrict__ knum,
               int*         __restrict__ ticket,
               float*       __restrict__ out)
{
    const int bc   = blockIdx.x;
    const int b    = bc / NCLS;
    const int c    = bc - b * NCLS;
    const int lane = threadIdx.x;
    const int bN   = b * NN;
    const uint64_t lmask = (1ull << lane) - 1ull;

    __shared__ uint64_t mem[CAP];
    __shared__ float4   bx_s[132];
    __shared__ float    ar_s[132];
    __shared__ uint64_t keepw[4];
    __shared__ int      nc_s;
    // packer-phase arrays
    __shared__ int      hist[256];
    __shared__ uint64_t cand[512];
    __shared__ int      nks2[NCLS];
    __shared__ int      ncand_s, cutoff_s;

    if (lane == 0) nc_s = 0;
    if (lane < 4) keepw[lane] = 0ull;
    __syncthreads();

    // ---- scan batch, compact this class's valid keys into LDS ----
    const float4* s4 = (const float4*)(scores + bN);
    const int4*   c4 = (const int4*)(classes + bN);
#pragma unroll 4
    for (int i = 0; i < (NN / 4) / 64; ++i) {       // 16 iterations
        const int vi = lane + (i << 6);
        const float4 sv = s4[vi];
        const int4   cv = c4[vi];
        const float ss[4] = {sv.x, sv.y, sv.z, sv.w};
        const int   cc[4] = {cv.x, cv.y, cv.z, cv.w};
        const int base = vi << 2;
#pragma unroll
        for (int e = 0; e < 4; ++e) {
            if (cc[e] == c && ss[e] > 0.05f) {
                unsigned u = __float_as_uint(ss[e]);
                unsigned m = (u & 0x80000000u) ? ~u : (u | 0x80000000u);
                uint64_t key = ((uint64_t)m << 32) | (unsigned)(base + e);
                int slot = atomicAdd(&nc_s, 1);
                if (slot < CAP) mem[slot] = key;
            }
        }
    }
    __syncthreads();
    int nc = nc_s > CAP ? CAP : nc_s;
    uint64_t* ks = kseg + (uint64_t)bc * CAP;
    const float4* boxes4 = (const float4*)boxes;

    if (nc <= 0) {
        if (lane == 0) knum[bc] = 0;
    } else if (nc <= 64) {
        // ---- fast path: in-wave descending bitonic sort of 64 u64 keys
        uint64_t key = (lane < nc) ? mem[lane] : 0ull;
        for (int k = 2; k <= 64; k <<= 1) {
            bool up = ((lane & k) == 0);
            for (int j = k >> 1; j >= 1; j >>= 1) {
                uint64_t w = shfl_xor64(key, j);
                bool km = (((lane & j) == 0) == up);
                key = km ? (key > w ? key : w) : (key < w ? key : w);
            }
        }
        unsigned idx = (unsigned)key;    // low 32 bits = batch-local index
        float4 bx = make_float4(0, 0, 0, 0);
        float  area = 0.0f;
        if (lane < nc) {
            bx = boxes4[bN + idx];
            {
#pragma clang fp contract(off)
                area = (bx.z - bx.x) * (bx.w - bx.y);
            }
        }
        bx_s[lane] = bx;
        ar_s[lane] = area;
        __syncthreads();
        uint64_t ov = 0;
        for (int j0 = 0; j0 < nc - 1; j0 += 4) {
            float4 t[4]; float ta[4];
#pragma unroll
            for (int r = 0; r < 4; ++r) { t[r] = bx_s[j0 + r]; ta[r] = ar_s[j0 + r]; }
#pragma unroll
            for (int r = 0; r < 4; ++r) {
                int j = j0 + r;
                if (j < nc - 1 && lane > j && lane < nc &&
                    iou_gt(bx.x, bx.y, bx.z, bx.w,
                           t[r].x, t[r].y, t[r].z, t[r].w, ta[r]))
                    ov |= 1ull << j;
            }
        }
        uint64_t alive = (nc >= 64) ? ~0ull : ((1ull << nc) - 1ull);
        for (int t = 0; t < nc; ++t) {
            if (!((alive >> t) & 1ull)) continue;
            uint64_t die = __ballot(((ov >> t) & 1ull) != 0);
            alive &= ~die;
        }
        int nk = __popcll(alive);
        if (lane < nc && ((alive >> lane) & 1ull))
            ks[__popcll(alive & lmask)] = key;
        if (lane == 0) knum[bc] = nk;
    } else if (nc <= 128) {
        // ---- medium path: two-register descending bitonic of 128 u64 keys
        uint64_t kA = (lane < nc) ? mem[lane] : 0ull;
        uint64_t kB = (64 + lane < nc) ? mem[64 + lane] : 0ull;
        for (int k = 2; k <= 128; k <<= 1) {
            bool up0 = ((lane & k) == 0);
            bool up1 = (((64 + lane) & k) == 0);
            for (int j = k >> 1; j >= 1; j >>= 1) {
                if (j == 64) {
                    ce64(kA, kB, up0);   // k==128 here: up0 == true
                } else {
                    uint64_t wA = shfl_xor64(kA, j);
                    uint64_t wB = shfl_xor64(kB, j);
                    bool kmA = (((lane & j) == 0) == up0);
                    bool kmB = (((lane & j) == 0) == up1);
                    kA = kmA ? (kA > wA ? kA : wA) : (kA < wA ? kA : wA);
                    kB = kmB ? (kB > wB ? kB : wB) : (kB < wB ? kB : wB);
                }
            }
        }
        const int mB = 64 + lane;
        unsigned idxA = (unsigned)kA, idxB = (unsigned)kB;
        float4 bA = make_float4(0, 0, 0, 0), bB = bA;
        float  aA = 0.0f, aB = 0.0f;
        if (lane < nc) {
            bA = boxes4[bN + idxA];
            {
#pragma clang fp contract(off)
                aA = (bA.z - bA.x) * (bA.w - bA.y);
            }
        }
        if (mB < nc) {
            bB = boxes4[bN + idxB];
            {
#pragma clang fp contract(off)
                aB = (bB.z - bB.x) * (bB.w - bB.y);
            }
        }
        bx_s[lane] = bA;      ar_s[lane] = aA;
        bx_s[64 + lane] = bB; ar_s[64 + lane] = aB;
        __syncthreads();
        uint64_t ovA0 = 0, ovB0 = 0, ovB1 = 0;
        for (int j0 = 0; j0 < nc - 1; j0 += 4) {
            float4 t[4]; float ta[4];
#pragma unroll
            for (int r = 0; r < 4; ++r) { t[r] = bx_s[j0 + r]; ta[r] = ar_s[j0 + r]; }
#pragma unroll
            for (int r = 0; r < 4; ++r) {
                int j = j0 + r;
                if (j >= nc - 1) continue;
                if (j < 64) {
                    if (lane > j && lane < nc &&
                        iou_gt(bA.x, bA.y, bA.z, bA.w, t[r].x, t[r].y, t[r].z, t[r].w, ta[r]))
                        ovA0 |= 1ull << j;
                    if (mB < nc &&
                        iou_gt(bB.x, bB.y, bB.z, bB.w, t[r].x, t[r].y, t[r].z, t[r].w, ta[r]))
                        ovB0 |= 1ull << j;
                } else {
                    if (mB > j && mB < nc &&
                        iou_gt(bB.x, bB.y, bB.z, bB.w, t[r].x, t[r].y, t[r].z, t[r].w, ta[r]))
                        ovB1 |= 1ull << (j - 64);
                }
            }
        }
        uint64_t alive0 = (nc >= 64) ? ~0ull : ((1ull << nc) - 1ull);
        uint64_t alive1 = (nc >= 128) ? ~0ull : ((1ull << (nc - 64)) - 1ull);
        for (int t = 0; t < nc; ++t) {
            if (t < 64) {
                if (!((alive0 >> t) & 1ull)) continue;
                uint64_t d0 = __ballot(((ovA0 >> t) & 1ull) != 0);
                uint64_t d1 = __ballot(((ovB0 >> t) & 1ull) != 0);
                alive0 &= ~d0;
                alive1 &= ~d1;
            } else {
                int tt = t - 64;
                if (!((alive1 >> tt) & 1ull)) continue;
                uint64_t d1 = __ballot(((ovB1 >> tt) & 1ull) != 0);
                alive1 &= ~d1;
            }
        }
        int c0 = __popcll(alive0);
        int nk = c0 + __popcll(alive1);
        if (lane < nc && ((alive0 >> lane) & 1ull))
            ks[__popcll(alive0 & lmask)] = kA;
        if (mB < nc && ((alive1 >> lane) & 1ull))
            ks[c0 + __popcll(alive1 & lmask)] = kB;
        if (lane == 0) knum[bc] = nk;
    } else {
        // ---- generic fallback (nc in 129..160; statistically never taken)
        for (int r = 0; r < nc; ++r) {             // odd-even sort, descending
            int st = r & 1;
            for (int m = st + 2 * lane; m + 1 < nc; m += 128) {
                uint64_t x = mem[m], y = mem[m + 1];
                if (x < y) { mem[m] = y; mem[m + 1] = x; }
            }
            __syncthreads();
        }
        float4 bx0 = make_float4(0, 0, 0, 0), bx1 = bx0, bx2 = bx0, bx3 = bx0;
        {
            int m = lane;
            if (m < nc) bx0 = boxes4[bN + (unsigned)mem[m]];
            m = 64 + lane;
            if (m < nc) bx1 = boxes4[bN + (unsigned)mem[m]];
            m = 128 + lane;
            if (m < nc) bx2 = boxes4[bN + (unsigned)mem[m]];
        }
        uint64_t supp = 0;
        int jmaxc = (nc + 63) >> 6;
        for (int t = 0; t < nc; ++t) {
            int jt = t >> 6, lt = t & 63;
            uint64_t am = __ballot(((supp >> jt) & 1ull) == 0);
            if (!((am >> lt) & 1ull)) continue;
            float4 sr = (jt == 0) ? bx0 : (jt == 1) ? bx1 : (jt == 2) ? bx2 : bx3;
            float t0 = __shfl(sr.x, lt), t1 = __shfl(sr.y, lt);
            float t2 = __shfl(sr.z, lt), t3 = __shfl(sr.w, lt);
            if (lane == 0) atomicOr(&keepw[jt], 1ull << lt);
            float tarea;
            {
#pragma clang fp contract(off)
                tarea = (t2 - t0) * (t3 - t1);
            }
            for (int j = jt; j < jmaxc; ++j) {
                int m = (j << 6) + lane;
                if (m <= t || m >= nc) continue;
                if ((supp >> j) & 1ull) continue;
                float4 cr = (j == 0) ? bx0 : (j == 1) ? bx1 : (j == 2) ? bx2 : bx3;
                if (iou_gt(cr.x, cr.y, cr.z, cr.w, t0, t1, t2, t3, tarea))
                    supp |= (1ull << j);
            }
        }
        __syncthreads();
        uint64_t w0 = keepw[0], w1 = keepw[1], w2 = keepw[2];
        int c0 = __popcll(w0), c1 = __popcll(w1);
        int nk = c0 + c1 + __popcll(w2);
        if ((w0 >> lane) & 1ull)
            ks[__popcll(w0 & lmask)] = mem[lane];
        if (64 + lane < nc && ((w1 >> lane) & 1ull))
            ks[c0 + __popcll(w1 & lmask)] = mem[64 + lane];
        if (128 + lane < nc && ((w2 >> lane) & 1ull))
            ks[c0 + c1 + __popcll(w2 & lmask)] = mem[128 + lane];
        if (lane == 0) knum[bc] = nk;
    }

    // ---- arrival: the 80th arriver for this batch becomes the packer ----
    __syncthreads();                 // drains vmcnt: all lanes' kseg/knum stores issued+complete
    __threadfence();                 // release to device scope
    int old = 0;
    if (lane == 0) old = atomicAdd(&ticket[b], 1);
    old = __shfl(old, 0, 64);
    if (old != NCLS - 1) return;
    __threadfence();                 // acquire: see all 80 blocks' kseg/knum

    // ================= packer (one wave) =================
    // load per-class kept counts
    int n0 = knum[b * NCLS + lane];                       // lane < 64 < NCLS
    int n1 = (64 + lane < NCLS) ? knum[b * NCLS + 64 + lane] : 0;
    nks2[lane] = n0;
    if (64 + lane < NCLS) nks2[64 + lane] = n1;
    int part = n0 + n1;
#pragma unroll
    for (int off = 1; off < 64; off <<= 1) part += __shfl_xor(part, off, 64);
    const int kept_n = part;
    const int target = kept_n < MAXDET ? kept_n : MAXDET;

    // static output fills (harness poisons d_out before every timed replay).
    // slot s is filled by lane (s & 63) and later overwritten (if kept) by the
    // SAME lane (rank & 63 == lane) -> program order keeps the real value.
    for (int s = lane; s < MAXDET; s += 64) {
        out[OFF_IDX + b * MAXDET + s] = -1.0f;
        out[OFF_SCR + b * MAXDET + s] = 0.0f;
        int ob = OFF_BOX + (b * MAXDET + s) * 4;
        out[ob + 0] = 0.0f; out[ob + 1] = 0.0f;
        out[ob + 2] = 0.0f; out[ob + 3] = 0.0f;
        out[OFF_CLS + b * MAXDET + s] = 0.0f;
    }
    if (lane == 0) out[OFF_NDT + b] = (float)target;

#pragma unroll
    for (int r = 0; r < 4; ++r) hist[(r << 6) + lane] = 0;
    if (lane == 0) { ncand_s = 0; cutoff_s = 256; }
    __syncthreads();

    // histogram of kept scores by value bucket (uniform scores -> ~15/bin)
    const uint64_t* ksegb = kseg + (uint64_t)(b * NCLS) * CAP;
    for (int c2 = 0; c2 < NCLS; ++c2) {
        int n = nks2[c2];
        const uint64_t* seg = ksegb + (uint64_t)c2 * CAP;
        for (int i = lane; i < n; i += 64) {
            unsigned m = (unsigned)(seg[i] >> 32);
            float f = __uint_as_float(m & 0x7FFFFFFFu);   // valid scores are positive
            int bin = (int)(f * 256.0f);
            bin = bin > 255 ? 255 : bin;
            atomicAdd(&hist[bin], 1);
        }
    }
    __syncthreads();

    // exact 1-bin-granularity cutoff: the bin g with suffix(g) >= target and
    // suffix(g+1) < target. Candidates then number target..target+hist[g] (<512).
    {
        int h0 = hist[4 * lane + 0], h1 = hist[4 * lane + 1];
        int h2 = hist[4 * lane + 2], h3 = hist[4 * lane + 3];
        int s = h0 + h1 + h2 + h3;
        for (int off = 1; off < 64; off <<= 1) {
            int t = __shfl_down(s, off, 64);
            if (lane + off < 64) s += t;
        }
        int snext = __shfl_down(s, 1, 64);
        if (lane == 63) snext = 0;
        int u0 = s;            // suffix(4L)
        int u1 = u0 - h0;      // suffix(4L+1)
        int u2 = u1 - h1;      // suffix(4L+2)
        int u3 = u2 - h2;      // suffix(4L+3)
        int u4 = snext;        // suffix(4L+4)
        if (target > 0) {
            if (u0 >= target && u1 < target) cutoff_s = 4 * lane + 0;
            if (u1 >= target && u2 < target) cutoff_s = 4 * lane + 1;
            if (u2 >= target && u3 < target) cutoff_s = 4 * lane + 2;
            if (u3 >= target && u4 < target) cutoff_s = 4 * lane + 3;
        }
    }
    __syncthreads();
    const int cutoff = cutoff_s;

    // gather candidate keys (bins >= cutoff)
    for (int c2 = 0; c2 < NCLS; ++c2) {
        int n = nks2[c2];
        const uint64_t* seg = ksegb + (uint64_t)c2 * CAP;
        for (int i = lane; i < n; i += 64) {
            uint64_t key = seg[i];
            unsigned m = (unsigned)(key >> 32);
            float f = __uint_as_float(m & 0x7FFFFFFFu);
            int bin = (int)(f * 256.0f);
            bin = bin > 255 ? 255 : bin;
            if (bin >= cutoff) {
                int slot = atomicAdd(&ncand_s, 1);
                if (slot < 512) cand[slot] = key;
            }
        }
    }
    __syncthreads();
    const int ncand = ncand_s < 512 ? ncand_s : 512;
    for (int i = lane; i < 512; i += 64)
        if (i >= ncand) cand[i] = 0ull;
    __syncthreads();

    // descending bitonic sort of 512 u64 keys in one wave (8 regs/lane)
    // element index i = (e<<6) | lane: bits [5:0]=lane (shfl), [8:6]=e (regs)
    uint64_t v[8];
#pragma unroll
    for (int e = 0; e < 8; ++e) v[e] = cand[(e << 6) | lane];
    for (int k = 2; k <= 512; k <<= 1) {
        for (int j = k >> 1; j >= 1; j >>= 1) {
            if (j >= 64) {
                const int m = j >> 6;
#pragma unroll
                for (int e = 0; e < 8; ++e) {
                    if ((e & m) == 0) {
                        const int i_lo = (e << 6) | lane;
                        bool desc = ((i_lo & k) == 0);
                        ce64(v[e], v[e | m], desc);
                    }
                }
            } else {
#pragma unroll
                for (int e = 0; e < 8; ++e) {
                    const int i_e = (e << 6) | lane;
                    bool up = ((i_e & k) == 0);
                    uint64_t w = shfl_xor64(v[e], j);
                    bool km = (((lane & j) == 0) == up);
                    v[e] = km ? (v[e] > w ? v[e] : w) : (v[e] < w ? v[e] : w);
                }
            }
        }
    }

    // write top-target detections (rank = sorted position; rank & 63 == lane)
#pragma unroll
    for (int e = 0; e < 8; ++e) {
        int rank = (e << 6) | lane;
        if (rank < target) {
            unsigned idx = (unsigned)v[e];
            out[OFF_SCR + b * MAXDET + rank] = scores[bN + idx];
            float4 g = boxes4[bN + idx];
            int ob = OFF_BOX + (b * MAXDET + rank) * 4;
            out[ob + 0] = g.x; out[ob + 1] = g.y;
            out[ob + 2] = g.z; out[ob + 3] = g.w;
            out[OFF_CLS + b * MAXDET + rank] = (float)classes[bN + idx];
        }
    }
}

extern "C" void kernel_launch(void* const* d_in, const int* in_sizes, int n_in,
                              void* d_out, int out_size, void* d_ws, size_t ws_size,
                              hipStream_t stream)
{
    const float* scores  = (const float*)d_in[0];
    const float* boxes   = (const float*)d_in[1];
    const int*   classes = (const int*)d_in[2];
    float*       out     = (float*)d_out;

    char* ws = (char*)d_ws;
    uint64_t* kseg   = (uint64_t*)(ws + WS_KSEG);
    int*      knum   = (int*)(ws + WS_KNUM);
    int*      ticket = (int*)(ws + WS_TICK);

    // workspace is poisoned before every replay -> re-zero the 8 tickets
    hipMemsetAsync(ticket, 0, NB * sizeof(int), stream);
    hipLaunchKernelGGL(k_nms_all, dim3(NB * NCLS), dim3(64), 0, stream,
                       scores, boxes, classes, kseg, knum, ticket, out);
}

// Round 3
// 121.754 us; speedup vs baseline: 1.3445x; 1.3445x over previous
//
#include <hip/hip_runtime.h>
#include <cstdint>

// Problem constants (fixed by reference)
#define NB      8
#define NN      4096
#define NCLS    80
#define MAXDET  300
#define CAP     160     // per-(batch,class) list capacity; counts ~49 +/- 7 (16 sigma)

// Output float layout (flat, 16808 elements)
#define OFF_IDX  0
#define OFF_SCR  2400
#define OFF_BOX  4800
#define OFF_CLS  14400
#define OFF_NDT  16800

// Workspace layout (bytes)
#define WS_KSEG  0                          // u64 [NB*NCLS][CAP] kept keys per class (segmented)
#define WS_KNUM  (NB * NCLS * CAP * 8)      // i32 [NB*NCLS] kept count per class (single writer)
#define WS_TICK  (WS_KNUM + NB * NCLS * 4)  // i32 [NB] arrival tickets (memset to 0 each replay)

// IoU > thr test, matching reference arithmetic exactly (no FMA contraction).
__device__ __forceinline__ bool iou_gt(float c0, float c1, float c2, float c3,
                                       float t0, float t1, float t2, float t3,
                                       float tarea)
{
#pragma clang fp contract(off)
    float xx1 = fmaxf(c0, t0);
    float yy1 = fmaxf(c1, t1);
    float xx2 = fminf(c2, t2);
    float yy2 = fminf(c3, t3);
    float w = xx2 - xx1; w = fmaxf(w, 0.0f);
    float h = yy2 - yy1; h = fmaxf(h, 0.0f);
    float inter = w * h;
    float areac = (c2 - c0) * (c3 - c1);
    float uni = areac + tarea - inter;
    return (inter / uni) > 0.65f;
}

__device__ __forceinline__ uint64_t shfl_xor64(uint64_t x, int m)
{
    unsigned lo = __shfl_xor((unsigned)x, m, 64);
    unsigned hi = __shfl_xor((unsigned)(x >> 32), m, 64);
    return ((uint64_t)hi << 32) | lo;
}

__device__ __forceinline__ void ce64(uint64_t& a, uint64_t& b, bool desc)
{
    uint64_t lo = (a < b) ? a : b;
    uint64_t hi = (a < b) ? b : a;
    a = desc ? hi : lo;
    b = desc ? lo : hi;
}

// ================== single fused kernel ==================
// 640 blocks x 64 threads, one block per (batch,class):
//   phase 1: scan batch scores/classes (L2-resident), compact this class's
//            valid keys to LDS, sort, greedy NMS, write private kseg/knum.
//   phase 2: __threadfence + ticket atomicAdd; the 80th arriver for a batch
//            becomes that batch's packer: lane-parallel key staging (lane =
//            class) + fused histogram -> 1-bin cutoff -> <=512 candidates ->
//            fully-unrolled in-register bitonic-512 -> pack outputs.
__global__ __launch_bounds__(64)
void k_nms_all(const float* __restrict__ scores,
               const float* __restrict__ boxes,
               const int*   __restrict__ classes,
               uint64_t*    __restrict__ kseg,
               int*         __restrict__ knum,
               int*         __restrict__ ticket,
               float*       __restrict__ out)
{
    const int bc   = blockIdx.x;
    const int b    = bc / NCLS;
    const int c    = bc - b * NCLS;
    const int lane = threadIdx.x;
    const int bN   = b * NN;
    const uint64_t lmask = (1ull << lane) - 1ull;

    __shared__ uint64_t mem[CAP];
    __shared__ float4   bx_s[132];
    __shared__ float    ar_s[132];
    __shared__ uint64_t keepw[4];
    __shared__ int      nc_s;
    // packer-phase arrays
    __shared__ int      hist[256];
    __shared__ uint64_t cand[512];
    __shared__ uint64_t dense[NN];
    __shared__ int      ncand_s;

    if (lane == 0) nc_s = 0;
    if (lane < 4) keepw[lane] = 0ull;
    __syncthreads();

    // ---- scan batch, compact this class's valid keys into LDS ----
    const float4* s4 = (const float4*)(scores + bN);
    const int4*   c4 = (const int4*)(classes + bN);
#pragma unroll 4
    for (int i = 0; i < (NN / 4) / 64; ++i) {       // 16 iterations
        const int vi = lane + (i << 6);
        const float4 sv = s4[vi];
        const int4   cv = c4[vi];
        const float ss[4] = {sv.x, sv.y, sv.z, sv.w};
        const int   cc[4] = {cv.x, cv.y, cv.z, cv.w};
        const int base = vi << 2;
#pragma unroll
        for (int e = 0; e < 4; ++e) {
            if (cc[e] == c && ss[e] > 0.05f) {
                unsigned u = __float_as_uint(ss[e]);
                unsigned m = (u & 0x80000000u) ? ~u : (u | 0x80000000u);
                uint64_t key = ((uint64_t)m << 32) | (unsigned)(base + e);
                int slot = atomicAdd(&nc_s, 1);
                if (slot < CAP) mem[slot] = key;
            }
        }
    }
    __syncthreads();
    int nc = nc_s > CAP ? CAP : nc_s;
    uint64_t* ks = kseg + (uint64_t)bc * CAP;
    const float4* boxes4 = (const float4*)boxes;

    if (nc <= 0) {
        if (lane == 0) knum[bc] = 0;
    } else if (nc <= 64) {
        // ---- fast path: in-wave descending bitonic sort of 64 u64 keys
        uint64_t key = (lane < nc) ? mem[lane] : 0ull;
        for (int k = 2; k <= 64; k <<= 1) {
            bool up = ((lane & k) == 0);
            for (int j = k >> 1; j >= 1; j >>= 1) {
                uint64_t w = shfl_xor64(key, j);
                bool km = (((lane & j) == 0) == up);
                key = km ? (key > w ? key : w) : (key < w ? key : w);
            }
        }
        unsigned idx = (unsigned)key;    // low 32 bits = batch-local index
        float4 bx = make_float4(0, 0, 0, 0);
        float  area = 0.0f;
        if (lane < nc) {
            bx = boxes4[bN + idx];
            {
#pragma clang fp contract(off)
                area = (bx.z - bx.x) * (bx.w - bx.y);
            }
        }
        bx_s[lane] = bx;
        ar_s[lane] = area;
        __syncthreads();
        uint64_t ov = 0;
        for (int j0 = 0; j0 < nc - 1; j0 += 4) {
            float4 t[4]; float ta[4];
#pragma unroll
            for (int r = 0; r < 4; ++r) { t[r] = bx_s[j0 + r]; ta[r] = ar_s[j0 + r]; }
#pragma unroll
            for (int r = 0; r < 4; ++r) {
                int j = j0 + r;
                if (j < nc - 1 && lane > j && lane < nc &&
                    iou_gt(bx.x, bx.y, bx.z, bx.w,
                           t[r].x, t[r].y, t[r].z, t[r].w, ta[r]))
                    ov |= 1ull << j;
            }
        }
        uint64_t alive = (nc >= 64) ? ~0ull : ((1ull << nc) - 1ull);
        for (int t = 0; t < nc; ++t) {
            if (!((alive >> t) & 1ull)) continue;
            uint64_t die = __ballot(((ov >> t) & 1ull) != 0);
            alive &= ~die;
        }
        int nk = __popcll(alive);
        if (lane < nc && ((alive >> lane) & 1ull))
            ks[__popcll(alive & lmask)] = key;
        if (lane == 0) knum[bc] = nk;
    } else if (nc <= 128) {
        // ---- medium path: two-register descending bitonic of 128 u64 keys
        uint64_t kA = (lane < nc) ? mem[lane] : 0ull;
        uint64_t kB = (64 + lane < nc) ? mem[64 + lane] : 0ull;
        for (int k = 2; k <= 128; k <<= 1) {
            bool up0 = ((lane & k) == 0);
            bool up1 = (((64 + lane) & k) == 0);
            for (int j = k >> 1; j >= 1; j >>= 1) {
                if (j == 64) {
                    ce64(kA, kB, up0);   // k==128 here: up0 == true
                } else {
                    uint64_t wA = shfl_xor64(kA, j);
                    uint64_t wB = shfl_xor64(kB, j);
                    bool kmA = (((lane & j) == 0) == up0);
                    bool kmB = (((lane & j) == 0) == up1);
                    kA = kmA ? (kA > wA ? kA : wA) : (kA < wA ? kA : wA);
                    kB = kmB ? (kB > wB ? kB : wB) : (kB < wB ? kB : wB);
                }
            }
        }
        const int mB = 64 + lane;
        unsigned idxA = (unsigned)kA, idxB = (unsigned)kB;
        float4 bA = make_float4(0, 0, 0, 0), bB = bA;
        float  aA = 0.0f, aB = 0.0f;
        if (lane < nc) {
            bA = boxes4[bN + idxA];
            {
#pragma clang fp contract(off)
                aA = (bA.z - bA.x) * (bA.w - bA.y);
            }
        }
        if (mB < nc) {
            bB = boxes4[bN + idxB];
            {
#pragma clang fp contract(off)
                aB = (bB.z - bB.x) * (bB.w - bB.y);
            }
        }
        bx_s[lane] = bA;      ar_s[lane] = aA;
        bx_s[64 + lane] = bB; ar_s[64 + lane] = aB;
        __syncthreads();
        uint64_t ovA0 = 0, ovB0 = 0, ovB1 = 0;
        for (int j0 = 0; j0 < nc - 1; j0 += 4) {
            float4 t[4]; float ta[4];
#pragma unroll
            for (int r = 0; r < 4; ++r) { t[r] = bx_s[j0 + r]; ta[r] = ar_s[j0 + r]; }
#pragma unroll
            for (int r = 0; r < 4; ++r) {
                int j = j0 + r;
                if (j >= nc - 1) continue;
                if (j < 64) {
                    if (lane > j && lane < nc &&
                        iou_gt(bA.x, bA.y, bA.z, bA.w, t[r].x, t[r].y, t[r].z, t[r].w, ta[r]))
                        ovA0 |= 1ull << j;
                    if (mB < nc &&
                        iou_gt(bB.x, bB.y, bB.z, bB.w, t[r].x, t[r].y, t[r].z, t[r].w, ta[r]))
                        ovB0 |= 1ull << j;
                } else {
                    if (mB > j && mB < nc &&
                        iou_gt(bB.x, bB.y, bB.z, bB.w, t[r].x, t[r].y, t[r].z, t[r].w, ta[r]))
                        ovB1 |= 1ull << (j - 64);
                }
            }
        }
        uint64_t alive0 = (nc >= 64) ? ~0ull : ((1ull << nc) - 1ull);
        uint64_t alive1 = (nc >= 128) ? ~0ull : ((1ull << (nc - 64)) - 1ull);
        for (int t = 0; t < nc; ++t) {
            if (t < 64) {
                if (!((alive0 >> t) & 1ull)) continue;
                uint64_t d0 = __ballot(((ovA0 >> t) & 1ull) != 0);
                uint64_t d1 = __ballot(((ovB0 >> t) & 1ull) != 0);
                alive0 &= ~d0;
                alive1 &= ~d1;
            } else {
                int tt = t - 64;
                if (!((alive1 >> tt) & 1ull)) continue;
                uint64_t d1 = __ballot(((ovB1 >> tt) & 1ull) != 0);
                alive1 &= ~d1;
            }
        }
        int c0 = __popcll(alive0);
        int nk = c0 + __popcll(alive1);
        if (lane < nc && ((alive0 >> lane) & 1ull))
            ks[__popcll(alive0 & lmask)] = kA;
        if (mB < nc && ((alive1 >> lane) & 1ull))
            ks[c0 + __popcll(alive1 & lmask)] = kB;
        if (lane == 0) knum[bc] = nk;
    } else {
        // ---- generic fallback (nc in 129..160; statistically never taken)
        for (int r = 0; r < nc; ++r) {             // odd-even sort, descending
            int st = r & 1;
            for (int m = st + 2 * lane; m + 1 < nc; m += 128) {
                uint64_t x = mem[m], y = mem[m + 1];
                if (x < y) { mem[m] = y; mem[m + 1] = x; }
            }
            __syncthreads();
        }
        float4 bx0 = make_float4(0, 0, 0, 0), bx1 = bx0, bx2 = bx0, bx3 = bx0;
        {
            int m = lane;
            if (m < nc) bx0 = boxes4[bN + (unsigned)mem[m]];
            m = 64 + lane;
            if (m < nc) bx1 = boxes4[bN + (unsigned)mem[m]];
            m = 128 + lane;
            if (m < nc) bx2 = boxes4[bN + (unsigned)mem[m]];
        }
        uint64_t supp = 0;
        int jmaxc = (nc + 63) >> 6;
        for (int t = 0; t < nc; ++t) {
            int jt = t >> 6, lt = t & 63;
            uint64_t am = __ballot(((supp >> jt) & 1ull) == 0);
            if (!((am >> lt) & 1ull)) continue;
            float4 sr = (jt == 0) ? bx0 : (jt == 1) ? bx1 : (jt == 2) ? bx2 : bx3;
            float t0 = __shfl(sr.x, lt), t1 = __shfl(sr.y, lt);
            float t2 = __shfl(sr.z, lt), t3 = __shfl(sr.w, lt);
            if (lane == 0) atomicOr(&keepw[jt], 1ull << lt);
            float tarea;
            {
#pragma clang fp contract(off)
                tarea = (t2 - t0) * (t3 - t1);
            }
            for (int j = jt; j < jmaxc; ++j) {
                int m = (j << 6) + lane;
                if (m <= t || m >= nc) continue;
                if ((supp >> j) & 1ull) continue;
                float4 cr = (j == 0) ? bx0 : (j == 1) ? bx1 : (j == 2) ? bx2 : bx3;
                if (iou_gt(cr.x, cr.y, cr.z, cr.w, t0, t1, t2, t3, tarea))
                    supp |= (1ull << j);
            }
        }
        __syncthreads();
        uint64_t w0 = keepw[0], w1 = keepw[1], w2 = keepw[2];
        int c0 = __popcll(w0), c1 = __popcll(w1);
        int nk = c0 + c1 + __popcll(w2);
        if ((w0 >> lane) & 1ull)
            ks[__popcll(w0 & lmask)] = mem[lane];
        if (64 + lane < nc && ((w1 >> lane) & 1ull))
            ks[c0 + __popcll(w1 & lmask)] = mem[64 + lane];
        if (128 + lane < nc && ((w2 >> lane) & 1ull))
            ks[c0 + c1 + __popcll(w2 & lmask)] = mem[128 + lane];
        if (lane == 0) knum[bc] = nk;
    }

    // ---- arrival: the 80th arriver for this batch becomes the packer ----
    __syncthreads();                 // all lanes' kseg/knum stores issued+complete
    __threadfence();                 // release to device scope
    int old = 0;
    if (lane == 0) old = atomicAdd(&ticket[b], 1);
    old = __shfl(old, 0, 64);
    if (old != NCLS - 1) return;
    __threadfence();                 // acquire: see all 80 blocks' kseg/knum

    // ================= packer (one wave) =================
    // static output fills first (stores fly under the rest of the packer).
    // slot s is filled by lane (s & 63) and later overwritten (if kept) by the
    // SAME lane (rank & 63 == lane) -> program order keeps the real value.
    for (int s = lane; s < MAXDET; s += 64) {
        out[OFF_IDX + b * MAXDET + s] = -1.0f;
        out[OFF_SCR + b * MAXDET + s] = 0.0f;
        int ob = OFF_BOX + (b * MAXDET + s) * 4;
        out[ob + 0] = 0.0f; out[ob + 1] = 0.0f;
        out[ob + 2] = 0.0f; out[ob + 3] = 0.0f;
        out[OFF_CLS + b * MAXDET + s] = 0.0f;
    }

    // per-class kept counts + offsets (lane = class) via wave prefix scans
    const int cA = lane;            // classes 0..63
    const int cB = 64 + lane;       // classes 64..79 (lanes 0..15)
    const int n0 = knum[b * NCLS + cA];
    const int n1 = (cB < NCLS) ? knum[b * NCLS + cB] : 0;
    int x = n0;
#pragma unroll
    for (int off = 1; off < 64; off <<= 1) {
        int t = __shfl_up(x, off, 64);
        if (lane >= off) x += t;
    }
    const int total0 = __shfl(x, 63, 64);
    const int pre0 = x - n0;
    int y = n1;
#pragma unroll
    for (int off = 1; off < 64; off <<= 1) {
        int t = __shfl_up(y, off, 64);
        if (lane >= off) y += t;
    }
    const int total1 = __shfl(y, 63, 64);
    const int pre1 = total0 + y - n1;
    const int kept_n = total0 + total1;          // <= 4096 by construction
    const int target = kept_n < MAXDET ? kept_n : MAXDET;
    if (lane == 0) out[OFF_NDT + b] = (float)target;

#pragma unroll
    for (int r = 0; r < 4; ++r) hist[(r << 6) | lane] = 0;
    if (lane == 0) ncand_s = 0;
    __syncthreads();

    // stage kept keys lane-parallel (lane = class), 8-wide load batches,
    // histogram fused into the staging pass.
    const uint64_t* ksegb = kseg + (uint64_t)(b * NCLS) * CAP;
    {
        const uint64_t* segA = ksegb + (uint64_t)cA * CAP;
        for (int i0 = 0; i0 < n0; i0 += 8) {
            uint64_t kr[8];
            const int mrem = n0 - i0;
#pragma unroll
            for (int t = 0; t < 8; ++t)
                if (t < mrem) kr[t] = segA[i0 + t];
#pragma unroll
            for (int t = 0; t < 8; ++t)
                if (t < mrem) {
                    dense[pre0 + i0 + t] = kr[t];
                    unsigned mm = (unsigned)(kr[t] >> 32);
                    float f = __uint_as_float(mm & 0x7FFFFFFFu);
                    int bin = (int)(f * 256.0f);
                    bin = bin > 255 ? 255 : bin;
                    atomicAdd(&hist[bin], 1);
                }
        }
        if (cB < NCLS) {
            const uint64_t* segB = ksegb + (uint64_t)cB * CAP;
            for (int i0 = 0; i0 < n1; i0 += 8) {
                uint64_t kr[8];
                const int mrem = n1 - i0;
#pragma unroll
                for (int t = 0; t < 8; ++t)
                    if (t < mrem) kr[t] = segB[i0 + t];
#pragma unroll
                for (int t = 0; t < 8; ++t)
                    if (t < mrem) {
                        dense[pre1 + i0 + t] = kr[t];
                        unsigned mm = (unsigned)(kr[t] >> 32);
                        float f = __uint_as_float(mm & 0x7FFFFFFFu);
                        int bin = (int)(f * 256.0f);
                        bin = bin > 255 ? 255 : bin;
                        atomicAdd(&hist[bin], 1);
                    }
            }
        }
    }
    __syncthreads();

    // exact 1-bin-granularity cutoff via wave suffix scan + min-reduce
    int cutoff;
    {
        int h0 = hist[4 * lane + 0], h1 = hist[4 * lane + 1];
        int h2 = hist[4 * lane + 2], h3 = hist[4 * lane + 3];
        int s = h0 + h1 + h2 + h3;
#pragma unroll
        for (int off = 1; off < 64; off <<= 1) {
            int t = __shfl_down(s, off, 64);
            if (lane + off < 64) s += t;
        }
        int snext = __shfl_down(s, 1, 64);
        if (lane == 63) snext = 0;
        int u0 = s;            // suffix(4L)
        int u1 = u0 - h0;      // suffix(4L+1)
        int u2 = u1 - h1;      // suffix(4L+2)
        int u3 = u2 - h2;      // suffix(4L+3)
        int u4 = snext;        // suffix(4L+4)
        int cl = 256;
        if (target > 0) {
            if (u0 >= target && u1 < target) cl = 4 * lane + 0;
            if (u1 >= target && u2 < target) cl = 4 * lane + 1;
            if (u2 >= target && u3 < target) cl = 4 * lane + 2;
            if (u3 >= target && u4 < target) cl = 4 * lane + 3;
        }
#pragma unroll
        for (int off = 1; off < 64; off <<= 1) {
            int t = __shfl_xor(cl, off, 64);
            cl = t < cl ? t : cl;
        }
        cutoff = cl;
    }

    // gather candidate keys (bins >= cutoff) from LDS
    for (int i = lane; i < kept_n; i += 64) {
        uint64_t key = dense[i];
        unsigned mm = (unsigned)(key >> 32);
        float f = __uint_as_float(mm & 0x7FFFFFFFu);
        int bin = (int)(f * 256.0f);
        bin = bin > 255 ? 255 : bin;
        if (bin >= cutoff) {
            int slot = atomicAdd(&ncand_s, 1);
            if (slot < 512) cand[slot] = key;
        }
    }
    __syncthreads();
    const int ncand = ncand_s < 512 ? ncand_s : 512;
    for (int i = lane; i < 512; i += 64)
        if (i >= ncand) cand[i] = 0ull;
    __syncthreads();

    // descending bitonic sort of 512 u64 keys in one wave (8 regs/lane).
    // element index i = (e<<6) | lane. FULLY UNROLLED so v[] stays in VGPRs
    // (runtime-indexed arrays would spill to scratch - rule #20).
    uint64_t v[8];
#pragma unroll
    for (int e = 0; e < 8; ++e) v[e] = cand[(e << 6) | lane];
#pragma unroll
    for (int kk = 1; kk <= 9; ++kk) {
        const int k = 1 << kk;
#pragma unroll
        for (int jj = kk - 1; jj >= 0; --jj) {
            const int j = 1 << jj;
            if (j >= 64) {
                const int m = j >> 6;        // 1, 2 or 4 (literal after unroll)
#pragma unroll
                for (int e = 0; e < 8; ++e) {
                    if ((e & m) == 0) {
                        const bool desc = (((e << 6) & k) == 0);
                        ce64(v[e], v[e | m], desc);
                    }
                }
            } else {
#pragma unroll
                for (int e = 0; e < 8; ++e) {
                    const int ebit = (e << 6) & k;        // static per e
                    bool up = (k < 64) ? ((lane & k) == 0) : (ebit == 0);
                    uint64_t w = shfl_xor64(v[e], j);
                    bool km = (((lane & j) == 0) == up);
                    v[e] = km ? (v[e] > w ? v[e] : w) : (v[e] < w ? v[e] : w);
                }
            }
        }
    }

    // write top-target detections (rank = sorted position; rank & 63 == lane)
#pragma unroll
    for (int e = 0; e < 8; ++e) {
        int rank = (e << 6) | lane;
        if (rank < target) {
            unsigned idx = (unsigned)v[e];
            out[OFF_SCR + b * MAXDET + rank] = scores[bN + idx];
            float4 g = boxes4[bN + idx];
            int ob = OFF_BOX + (b * MAXDET + rank) * 4;
            out[ob + 0] = g.x; out[ob + 1] = g.y;
            out[ob + 2] = g.z; out[ob + 3] = g.w;
            out[OFF_CLS + b * MAXDET + rank] = (float)classes[bN + idx];
        }
    }
}

extern "C" void kernel_launch(void* const* d_in, const int* in_sizes, int n_in,
                              void* d_out, int out_size, void* d_ws, size_t ws_size,
                              hipStream_t stream)
{
    const float* scores  = (const float*)d_in[0];
    const float* boxes   = (const float*)d_in[1];
    const int*   classes = (const int*)d_in[2];
    float*       out     = (float*)d_out;

    char* ws = (char*)d_ws;
    uint64_t* kseg   = (uint64_t*)(ws + WS_KSEG);
    int*      knum   = (int*)(ws + WS_KNUM);
    int*      ticket = (int*)(ws + WS_TICK);

    // workspace is poisoned before every replay -> re-zero the 8 tickets
    hipMemsetAsync(ticket, 0, NB * sizeof(int), stream);
    hipLaunchKernelGGL(k_nms_all, dim3(NB * NCLS), dim3(64), 0, stream,
                       scores, boxes, classes, kseg, knum, ticket, out);
}

// Round 4
// 112.515 us; speedup vs baseline: 1.4549x; 1.0821x over previous
//
#include <hip/hip_runtime.h>
#include <cstdint>

// Problem constants (fixed by reference)
#define NB      8
#define NN      4096
#define NCLS    80
#define MAXDET  300
#define CAP     160     // per-(batch,class) candidate capacity; counts ~49 +/- 7 (16 sigma)

// Output float layout (flat, 16808 elements)
#define OFF_IDX  0
#define OFF_SCR  2400
#define OFF_BOX  4800
#define OFF_CLS  14400
#define OFF_NDT  16800

// Workspace layout (bytes)
#define WS_KEPT  0                   // u64 [NB][NN] kept keys, dense per batch (atomic bump)
#define WS_CTL   (NB * NN * 8)       // i32 keptc[NB]; i32 ticket[NB]  (memset 0 each replay)

// IoU > thr test, matching reference arithmetic exactly (no FMA contraction).
__device__ __forceinline__ bool iou_gt(float c0, float c1, float c2, float c3,
                                       float t0, float t1, float t2, float t3,
                                       float tarea)
{
#pragma clang fp contract(off)
    float xx1 = fmaxf(c0, t0);
    float yy1 = fmaxf(c1, t1);
    float xx2 = fminf(c2, t2);
    float yy2 = fminf(c3, t3);
    float w = xx2 - xx1; w = fmaxf(w, 0.0f);
    float h = yy2 - yy1; h = fmaxf(h, 0.0f);
    float inter = w * h;
    float areac = (c2 - c0) * (c3 - c1);
    float uni = areac + tarea - inter;
    return (inter / uni) > 0.65f;
}

__device__ __forceinline__ uint64_t shfl_xor64(uint64_t x, int m)
{
    unsigned lo = __shfl_xor((unsigned)x, m, 64);
    unsigned hi = __shfl_xor((unsigned)(x >> 32), m, 64);
    return ((uint64_t)hi << 32) | lo;
}

__device__ __forceinline__ void ce64(uint64_t& a, uint64_t& b, bool desc)
{
    uint64_t lo = (a < b) ? a : b;
    uint64_t hi = (a < b) ? b : a;
    a = desc ? hi : lo;
    b = desc ? lo : hi;
}

// ================== single fused kernel, 640 blocks x 256 threads ==================
// phase 1 (per (b,c) block): 4-wave scan of the batch (L2-resident) compacts this
//   class's valid keys to LDS; wave 0 sorts + greedy-NMS; survivors go to the DENSE
//   per-batch kept[] via atomicAdd(&keptc[b], nk) bump (no per-class segments).
// phase 2: release fence + ticket; the 80th arriver packs with ALL 4 WAVES:
//   linear kept[] read + fused histogram -> exact-bin cutoff -> <=1024 candidates ->
//   256-thread x 4-elem bitonic (round-0's proven kc sort) -> pack outputs.
__global__ __launch_bounds__(256)
void k_nms_all(const float* __restrict__ scores,
               const float* __restrict__ boxes,
               const int*   __restrict__ classes,
               uint64_t*    __restrict__ kept,
               int*         __restrict__ ctl,
               float*       __restrict__ out)
{
    const int bc   = blockIdx.x;
    const int b    = bc / NCLS;
    const int c    = bc - b * NCLS;
    const int tid  = threadIdx.x;
    const int lane = tid & 63;
    const int wv   = tid >> 6;
    const int bN   = b * NN;
    const uint64_t lmask = (1ull << lane) - 1ull;

    int* keptc  = ctl;
    int* ticket = ctl + NB;

    __shared__ uint64_t mem[CAP];
    __shared__ float4   bx_s[132];
    __shared__ float    ar_s[132];
    __shared__ uint64_t keepw[4];
    __shared__ int      nc_s;
    __shared__ int      packer_s;
    // packer-phase arrays
    __shared__ int      hist[256];
    __shared__ uint64_t cand[1024];
    __shared__ int      ncand_s, cutoff_s;

    if (tid == 0) nc_s = 0;
    if (tid < 4) keepw[tid] = 0ull;
    __syncthreads();

    // ---- scan batch with all 4 waves, compact this class's keys into LDS ----
    const float4* s4 = (const float4*)(scores + bN);
    const int4*   c4 = (const int4*)(classes + bN);
#pragma unroll
    for (int i = 0; i < 4; ++i) {                    // 4 vec-iters per thread
        const int vi = tid + (i << 8);
        const float4 sv = s4[vi];
        const int4   cv = c4[vi];
        const float ss[4] = {sv.x, sv.y, sv.z, sv.w};
        const int   cc[4] = {cv.x, cv.y, cv.z, cv.w};
        const int base = vi << 2;
#pragma unroll
        for (int e = 0; e < 4; ++e) {
            if (cc[e] == c && ss[e] > 0.05f) {
                unsigned u = __float_as_uint(ss[e]);
                unsigned m = (u & 0x80000000u) ? ~u : (u | 0x80000000u);
                uint64_t key = ((uint64_t)m << 32) | (unsigned)(base + e);
                int slot = atomicAdd(&nc_s, 1);
                if (slot < CAP) mem[slot] = key;
            }
        }
    }
    __syncthreads();
    const int nc = nc_s > CAP ? CAP : nc_s;
    const float4* boxes4 = (const float4*)boxes;
    uint64_t* kb = kept + (uint64_t)b * NN;

    if (nc <= 0) {
        // nothing kept for this class
    } else if (nc <= 64) {
        // ---- fast path (wave 0): in-wave descending bitonic of 64 keys ----
        uint64_t key = 0ull;
        float4 bx = make_float4(0, 0, 0, 0);
        if (wv == 0) {
            key = (lane < nc) ? mem[lane] : 0ull;
            for (int k = 2; k <= 64; k <<= 1) {
                bool up = ((lane & k) == 0);
                for (int j = k >> 1; j >= 1; j >>= 1) {
                    uint64_t w = shfl_xor64(key, j);
                    bool km = (((lane & j) == 0) == up);
                    key = km ? (key > w ? key : w) : (key < w ? key : w);
                }
            }
            unsigned idx = (unsigned)key;     // low 32 bits = batch-local index
            float area = 0.0f;
            if (lane < nc) {
                bx = boxes4[bN + idx];
                {
#pragma clang fp contract(off)
                    area = (bx.z - bx.x) * (bx.w - bx.y);
                }
            }
            bx_s[lane] = bx;
            ar_s[lane] = area;
        }
        __syncthreads();
        if (wv == 0) {
            uint64_t ov = 0;
            for (int j0 = 0; j0 < nc - 1; j0 += 4) {
                float4 t[4]; float ta[4];
#pragma unroll
                for (int r = 0; r < 4; ++r) { t[r] = bx_s[j0 + r]; ta[r] = ar_s[j0 + r]; }
#pragma unroll
                for (int r = 0; r < 4; ++r) {
                    int j = j0 + r;
                    if (j < nc - 1 && lane > j && lane < nc &&
                        iou_gt(bx.x, bx.y, bx.z, bx.w,
                               t[r].x, t[r].y, t[r].z, t[r].w, ta[r]))
                        ov |= 1ull << j;
                }
            }
            uint64_t alive = (nc >= 64) ? ~0ull : ((1ull << nc) - 1ull);
            for (int t = 0; t < nc; ++t) {
                if (!((alive >> t) & 1ull)) continue;
                uint64_t die = __ballot(((ov >> t) & 1ull) != 0);
                alive &= ~die;
            }
            int nk = __popcll(alive);
            int base0 = 0;
            if (lane == 0) base0 = atomicAdd(&keptc[b], nk);
            base0 = __shfl(base0, 0, 64);
            if (lane < nc && ((alive >> lane) & 1ull))
                kb[base0 + __popcll(alive & lmask)] = key;
        }
    } else if (nc <= 128) {
        // ---- medium path (wave 0): two-register descending bitonic of 128 ----
        uint64_t kA = 0ull, kB = 0ull;
        float4 bA = make_float4(0, 0, 0, 0), bB = bA;
        const int mB = 64 + lane;
        if (wv == 0) {
            kA = (lane < nc) ? mem[lane] : 0ull;
            kB = (mB < nc) ? mem[mB] : 0ull;
            for (int k = 2; k <= 128; k <<= 1) {
                bool up0 = ((lane & k) == 0);
                bool up1 = ((mB & k) == 0);
                for (int j = k >> 1; j >= 1; j >>= 1) {
                    if (j == 64) {
                        ce64(kA, kB, up0);   // k==128 here: up0 == true
                    } else {
                        uint64_t wA = shfl_xor64(kA, j);
                        uint64_t wB = shfl_xor64(kB, j);
                        bool kmA = (((lane & j) == 0) == up0);
                        bool kmB = (((lane & j) == 0) == up1);
                        kA = kmA ? (kA > wA ? kA : wA) : (kA < wA ? kA : wA);
                        kB = kmB ? (kB > wB ? kB : wB) : (kB < wB ? kB : wB);
                    }
                }
            }
            unsigned idxA = (unsigned)kA, idxB = (unsigned)kB;
            float aA = 0.0f, aB = 0.0f;
            if (lane < nc) {
                bA = boxes4[bN + idxA];
                {
#pragma clang fp contract(off)
                    aA = (bA.z - bA.x) * (bA.w - bA.y);
                }
            }
            if (mB < nc) {
                bB = boxes4[bN + idxB];
                {
#pragma clang fp contract(off)
                    aB = (bB.z - bB.x) * (bB.w - bB.y);
                }
            }
            bx_s[lane] = bA;      ar_s[lane] = aA;
            bx_s[64 + lane] = bB; ar_s[64 + lane] = aB;
        }
        __syncthreads();
        if (wv == 0) {
            uint64_t ovA0 = 0, ovB0 = 0, ovB1 = 0;
            for (int j0 = 0; j0 < nc - 1; j0 += 4) {
                float4 t[4]; float ta[4];
#pragma unroll
                for (int r = 0; r < 4; ++r) { t[r] = bx_s[j0 + r]; ta[r] = ar_s[j0 + r]; }
#pragma unroll
                for (int r = 0; r < 4; ++r) {
                    int j = j0 + r;
                    if (j >= nc - 1) continue;
                    if (j < 64) {
                        if (lane > j && lane < nc &&
                            iou_gt(bA.x, bA.y, bA.z, bA.w, t[r].x, t[r].y, t[r].z, t[r].w, ta[r]))
                            ovA0 |= 1ull << j;
                        if (mB < nc &&
                            iou_gt(bB.x, bB.y, bB.z, bB.w, t[r].x, t[r].y, t[r].z, t[r].w, ta[r]))
                            ovB0 |= 1ull << j;
                    } else {
                        if (mB > j && mB < nc &&
                            iou_gt(bB.x, bB.y, bB.z, bB.w, t[r].x, t[r].y, t[r].z, t[r].w, ta[r]))
                            ovB1 |= 1ull << (j - 64);
                    }
                }
            }
            uint64_t alive0 = (nc >= 64) ? ~0ull : ((1ull << nc) - 1ull);
            uint64_t alive1 = (nc >= 128) ? ~0ull : ((1ull << (nc - 64)) - 1ull);
            for (int t = 0; t < nc; ++t) {
                if (t < 64) {
                    if (!((alive0 >> t) & 1ull)) continue;
                    uint64_t d0 = __ballot(((ovA0 >> t) & 1ull) != 0);
                    uint64_t d1 = __ballot(((ovB0 >> t) & 1ull) != 0);
                    alive0 &= ~d0;
                    alive1 &= ~d1;
                } else {
                    int tt = t - 64;
                    if (!((alive1 >> tt) & 1ull)) continue;
                    uint64_t d1 = __ballot(((ovB1 >> tt) & 1ull) != 0);
                    alive1 &= ~d1;
                }
            }
            int c0 = __popcll(alive0);
            int nk = c0 + __popcll(alive1);
            int base0 = 0;
            if (lane == 0) base0 = atomicAdd(&keptc[b], nk);
            base0 = __shfl(base0, 0, 64);
            if (lane < nc && ((alive0 >> lane) & 1ull))
                kb[base0 + __popcll(alive0 & lmask)] = kA;
            if (mB < nc && ((alive1 >> lane) & 1ull))
                kb[base0 + c0 + __popcll(alive1 & lmask)] = kB;
        }
    } else {
        // ---- generic fallback (nc in 129..160; statistically never taken) ----
        for (int r = 0; r < nc; ++r) {             // odd-even sort, descending
            int st = r & 1;
            for (int m = st + 2 * tid; m + 1 < nc; m += 512) {
                uint64_t x = mem[m], y = mem[m + 1];
                if (x < y) { mem[m] = y; mem[m + 1] = x; }
            }
            __syncthreads();
        }
        if (wv == 0) {
            float4 bx0 = make_float4(0, 0, 0, 0), bx1 = bx0, bx2 = bx0, bx3 = bx0;
            {
                int m = lane;
                if (m < nc) bx0 = boxes4[bN + (unsigned)mem[m]];
                m = 64 + lane;
                if (m < nc) bx1 = boxes4[bN + (unsigned)mem[m]];
                m = 128 + lane;
                if (m < nc) bx2 = boxes4[bN + (unsigned)mem[m]];
            }
            uint64_t supp = 0;
            int jmaxc = (nc + 63) >> 6;
            for (int t = 0; t < nc; ++t) {
                int jt = t >> 6, lt = t & 63;
                uint64_t am = __ballot(((supp >> jt) & 1ull) == 0);
                if (!((am >> lt) & 1ull)) continue;
                float4 sr = (jt == 0) ? bx0 : (jt == 1) ? bx1 : (jt == 2) ? bx2 : bx3;
                float t0 = __shfl(sr.x, lt), t1 = __shfl(sr.y, lt);
                float t2 = __shfl(sr.z, lt), t3 = __shfl(sr.w, lt);
                if (lane == 0) atomicOr(&keepw[jt], 1ull << lt);
                float tarea;
                {
#pragma clang fp contract(off)
                    tarea = (t2 - t0) * (t3 - t1);
                }
                for (int j = jt; j < jmaxc; ++j) {
                    int m = (j << 6) + lane;
                    if (m <= t || m >= nc) continue;
                    if ((supp >> j) & 1ull) continue;
                    float4 cr = (j == 0) ? bx0 : (j == 1) ? bx1 : (j == 2) ? bx2 : bx3;
                    if (iou_gt(cr.x, cr.y, cr.z, cr.w, t0, t1, t2, t3, tarea))
                        supp |= (1ull << j);
                }
            }
        }
        __syncthreads();
        if (wv == 0) {
            uint64_t w0 = keepw[0], w1 = keepw[1], w2 = keepw[2];
            int c0 = __popcll(w0), c1 = __popcll(w1);
            int nk = c0 + c1 + __popcll(w2);
            int base0 = 0;
            if (lane == 0) base0 = atomicAdd(&keptc[b], nk);
            base0 = __shfl(base0, 0, 64);
            if ((w0 >> lane) & 1ull)
                kb[base0 + __popcll(w0 & lmask)] = mem[lane];
            if (64 + lane < nc && ((w1 >> lane) & 1ull))
                kb[base0 + c0 + __popcll(w1 & lmask)] = mem[64 + lane];
            if (128 + lane < nc && ((w2 >> lane) & 1ull))
                kb[base0 + c0 + c1 + __popcll(w2 & lmask)] = mem[128 + lane];
        }
    }

    // ---- arrival: the 80th arriver for this batch becomes the packer ----
    __syncthreads();                 // wave-0's kb/keptc ops issued
    if (tid == 0) {
        __threadfence();             // release (waits wave-0 stores, then wbL2)
        packer_s = (atomicAdd(&ticket[b], 1) == NCLS - 1) ? 1 : 0;
    }
    __syncthreads();
    if (!packer_s) return;
    __threadfence();                 // acquire in ALL the packer's waves

    // ================= packer (4 waves) =================
    const int kept_n = keptc[b];                  // <= NN by construction
    const int target = kept_n < MAXDET ? kept_n : MAXDET;

    // static output fills (harness poisons d_out before every timed replay);
    // real values overwritten after >=4 barriers -> no intra-block race.
    for (int s = tid; s < MAXDET; s += 256) {
        out[OFF_IDX + b * MAXDET + s] = -1.0f;
        out[OFF_SCR + b * MAXDET + s] = 0.0f;
        int ob = OFF_BOX + (b * MAXDET + s) * 4;
        out[ob + 0] = 0.0f; out[ob + 1] = 0.0f;
        out[ob + 2] = 0.0f; out[ob + 3] = 0.0f;
        out[OFF_CLS + b * MAXDET + s] = 0.0f;
    }
    if (tid == 0) out[OFF_NDT + b] = (float)target;

    hist[tid] = 0;
    if (tid == 0) { ncand_s = 0; cutoff_s = 256; }
    __syncthreads();

    // pass A: linear read of kept[] + histogram (independent loads, 4 waves)
#pragma unroll 4
    for (int i = tid; i < kept_n; i += 256) {
        unsigned m = (unsigned)(kb[i] >> 32);
        float f = __uint_as_float(m & 0x7FFFFFFFu);   // valid scores are positive
        int bin = (int)(f * 256.0f);
        bin = bin > 255 ? 255 : bin;
        atomicAdd(&hist[bin], 1);
    }
    __syncthreads();

    // exact 1-bin-granularity cutoff (wave 0)
    if (wv == 0) {
        int h0 = hist[4 * lane + 0], h1 = hist[4 * lane + 1];
        int h2 = hist[4 * lane + 2], h3 = hist[4 * lane + 3];
        int s = h0 + h1 + h2 + h3;
#pragma unroll
        for (int off = 1; off < 64; off <<= 1) {
            int t = __shfl_down(s, off, 64);
            if (lane + off < 64) s += t;
        }
        int snext = __shfl_down(s, 1, 64);
        if (lane == 63) snext = 0;
        int u0 = s;            // suffix(4L)
        int u1 = u0 - h0;      // suffix(4L+1)
        int u2 = u1 - h1;      // suffix(4L+2)
        int u3 = u2 - h2;      // suffix(4L+3)
        int u4 = snext;        // suffix(4L+4)
        if (target > 0) {
            if (u0 >= target && u1 < target) cutoff_s = 4 * lane + 0;
            if (u1 >= target && u2 < target) cutoff_s = 4 * lane + 1;
            if (u2 >= target && u3 < target) cutoff_s = 4 * lane + 2;
            if (u3 >= target && u4 < target) cutoff_s = 4 * lane + 3;
        }
    }
    __syncthreads();
    const int cutoff = cutoff_s;

    // pass B: gather candidates (bins >= cutoff) from the now-L2-hot kept[]
#pragma unroll 4
    for (int i = tid; i < kept_n; i += 256) {
        uint64_t key = kb[i];
        unsigned m = (unsigned)(key >> 32);
        float f = __uint_as_float(m & 0x7FFFFFFFu);
        int bin = (int)(f * 256.0f);
        bin = bin > 255 ? 255 : bin;
        if (bin >= cutoff) {
            int slot = atomicAdd(&ncand_s, 1);
            if (slot < 1024) cand[slot] = key;
        }
    }
    __syncthreads();
    const int ncand = ncand_s < 1024 ? ncand_s : 1024;
    for (int i = tid; i < 1024; i += 256)
        if (i >= ncand) cand[i] = 0ull;
    __syncthreads();

    // descending bitonic sort of 1024 u64 keys (256 thr x 4 elems) — round-0 code
    // i bits: [1:0]=e (register), [7:2]=lane (shfl), [9:8]=wave (LDS)
    const int base = tid << 2;
    uint64_t v[4];
#pragma unroll
    for (int e = 0; e < 4; ++e) v[e] = cand[base + e];
    for (int k = 2; k <= 1024; k <<= 1) {
        for (int j = k >> 1; j >= 1; j >>= 1) {
            if (j >= 256) {
                __syncthreads();
#pragma unroll
                for (int e = 0; e < 4; ++e) cand[base + e] = v[e];
                __syncthreads();
                const int pb = base ^ j;
                const bool keepmax = (((base & j) == 0) == ((base & k) == 0));
                uint64_t w[4];
#pragma unroll
                for (int e = 0; e < 4; ++e) w[e] = cand[pb + e];
#pragma unroll
                for (int e = 0; e < 4; ++e) {
                    uint64_t a = v[e], cc = w[e];
                    v[e] = keepmax ? (a > cc ? a : cc) : (a < cc ? a : cc);
                }
            } else if (j >= 4) {
                const int m = j >> 2;
                const bool keepmax = (((lane & m) == 0) == ((base & k) == 0));
                unsigned wlo[4], whi[4];
#pragma unroll
                for (int e = 0; e < 4; ++e) wlo[e] = __shfl_xor((unsigned)v[e], m, 64);
#pragma unroll
                for (int e = 0; e < 4; ++e) whi[e] = __shfl_xor((unsigned)(v[e] >> 32), m, 64);
#pragma unroll
                for (int e = 0; e < 4; ++e) {
                    uint64_t w = ((uint64_t)whi[e] << 32) | wlo[e];
                    uint64_t a = v[e];
                    v[e] = keepmax ? (a > w ? a : w) : (a < w ? a : w);
                }
            } else if (j == 2) {
                bool d = ((base & k) == 0);
                ce64(v[0], v[2], d);
                ce64(v[1], v[3], d);
            } else {
                bool d0 = (((base + 0) & k) == 0);
                bool d2 = (((base + 2) & k) == 0);
                ce64(v[0], v[1], d0);
                ce64(v[2], v[3], d2);
            }
        }
    }

    // write top-target detections (rank = sorted position)
#pragma unroll
    for (int e = 0; e < 4; ++e) {
        int rank = base + e;
        if (rank < target) {
            unsigned idx = (unsigned)v[e];
            out[OFF_SCR + b * MAXDET + rank] = scores[bN + idx];
            float4 g = boxes4[bN + idx];
            int ob = OFF_BOX + (b * MAXDET + rank) * 4;
            out[ob + 0] = g.x; out[ob + 1] = g.y;
            out[ob + 2] = g.z; out[ob + 3] = g.w;
            out[OFF_CLS + b * MAXDET + rank] = (float)classes[bN + idx];
        }
    }
}

extern "C" void kernel_launch(void* const* d_in, const int* in_sizes, int n_in,
                              void* d_out, int out_size, void* d_ws, size_t ws_size,
                              hipStream_t stream)
{
    const float* scores  = (const float*)d_in[0];
    const float* boxes   = (const float*)d_in[1];
    const int*   classes = (const int*)d_in[2];
    float*       out     = (float*)d_out;

    char* ws = (char*)d_ws;
    uint64_t* kept = (uint64_t*)(ws + WS_KEPT);
    int*      ctl  = (int*)(ws + WS_CTL);

    // workspace is poisoned before every replay -> re-zero keptc[8] + ticket[8]
    hipMemsetAsync(ctl, 0, 2 * NB * sizeof(int), stream);
    hipLaunchKernelGGL(k_nms_all, dim3(NB * NCLS), dim3(256), 0, stream,
                       scores, boxes, classes, kept, ctl, out);
}